// Round 3
// baseline (1288.867 us; speedup 1.0000x reference)
//
#include <hip/hip_runtime.h>
#include <hip/hip_bf16.h>

// GlobalAttention: Q_LEN=512, SRC_LEN=2048, B=32, D=1024, F=2048
// Round 3: 256x256-tile 8-wave MFMA GEMM with double-buffered LDS,
// stage-early + counted vmcnt (T3+T4), setprio (T5), 0-conflict XOR swizzle.
//   K1: qr = query.W1^T + b1      3-term split (segments), bf16-pair out
//   K2: scores = qr . values      3-term split, f32 out
//   SM: softmax -> P bf16
//   K4: att = P . vT              1-term, bf16-hi out
//   K5: out = tanh([att,q].W2^T)  1-term, 2 K-segments (concat)
// Fallback (ws too small): fp32 VALU pipeline.

typedef __attribute__((ext_vector_type(8))) short bf16x8;
typedef __attribute__((ext_vector_type(4))) float f32x4;

__device__ __forceinline__ ushort f2bf(float x) {
    unsigned u = __builtin_bit_cast(unsigned, x);
    u += 0x7FFFu + ((u >> 16) & 1u);
    return (ushort)(u >> 16);
}
__device__ __forceinline__ float bf2f(ushort h) {
    unsigned u = (unsigned)h << 16;
    return __builtin_bit_cast(float, u);
}
__device__ __forceinline__ void async16(const ushort* g, ushort* l) {
    __builtin_amdgcn_global_load_lds(
        (const __attribute__((address_space(1))) unsigned int*)g,
        (__attribute__((address_space(3))) unsigned int*)l, 16, 0, 0);
}

// ---------------------------------------------------------------------------
// 256x256 tile, BK=32, 512 threads (8 waves, 2M x 4N -> wave tile 128x64).
// C[m,n] = sum_{s<nseg} sum_k A_s[m*lda+k] * B_s[n*ldb+k], k in [0,Kseg)
// (segments = K-concatenation; used for split-bf16 3-term and [att|q] concat)
// LDS: 2 buffers x (A 256x32 + B 256x32) bf16 = 64 KiB. Slot-XOR swizzle
// (slot' = slot ^ ((row>>1)&3)) applied to BOTH the global stage source and
// the ds_read -> 2-way max bank aliasing (free).
// Pipeline per K-tile: STAGE(kt+1 -> other buf); vmcnt(4); barrier;
// 4 phases {6 ds_read_b128 -> setprio(1) 8 MFMA setprio(0)}; barrier.
// OUTMODE: 0 = f32; 2 = bf16 hi (+lo if non-null), +bias if non-null;
//          3 = tanh(x + bias) f32
// ---------------------------------------------------------------------------
template<int OUTMODE>
__global__ __launch_bounds__(512, 2) void gemm256(
    const ushort* __restrict__ A0, const ushort* __restrict__ A1, const ushort* __restrict__ A2,
    const ushort* __restrict__ B0, const ushort* __restrict__ B1, const ushort* __restrict__ B2,
    long lda, long ldb, int nseg, int Kseg,
    const float* __restrict__ bias,
    float* __restrict__ Cf, ushort* __restrict__ Chi, ushort* __restrict__ Clo,
    long ldc, long sAb, long sBb, long sCb)
{
    __shared__ ushort lds[32768];   // 2 x (A 8192 + B 8192) = 64 KiB

    const int t  = threadIdx.x;
    const int l  = t & 63;
    const int wid = t >> 6;
    const int lr = l & 15;
    const int lg = l >> 4;
    const int sw = (lr >> 1) & 3;
    const int wm = (wid >> 2) * 128;
    const int wn = (wid & 3) * 64;

    const long m0 = (long)blockIdx.y * 256;
    const long n0 = (long)blockIdx.x * 256;
    const int  bz = blockIdx.z;

    const ushort* a0 = A0 + (long)bz * sAb;
    const ushort* a1 = A1 + (long)bz * sAb;
    const ushort* a2 = A2 + (long)bz * sAb;
    const ushort* b0 = B0 + (long)bz * sBb;
    const ushort* b1p = B1 + (long)bz * sBb;
    const ushort* b2p = B2 + (long)bz * sBb;

    // staging: operand tile = 256 rows x 4 16B-chunks; thread t covers chunks
    // t (rows 0..127) and t+512 (rows 128..255). chunk c -> LDS elems c*8
    // (linear); global source chunk = logical slot (c&3)^((row>>1)&3).
    auto coff = [](int c, long ld, long base) -> long {
        int r  = c >> 2;
        int sl = (c & 3) ^ ((r >> 1) & 3);
        return (base + r) * ld + sl * 8;
    };
    const long eA0 = coff(t, lda, m0), eA1 = coff(t + 512, lda, m0);
    const long eB0 = coff(t, ldb, n0), eB1 = coff(t + 512, ldb, n0);

    const int tps = Kseg >> 5;        // K-tiles per segment
    const int NTt = nseg * tps;

    auto STAGE = [&](int kt, int pbuf) {
        int s2 = (kt >= tps) + (kt >= 2 * tps);
        long ko = (long)(kt - s2 * tps) << 5;
        const ushort* Ak = (s2 == 0 ? a0 : (s2 == 1 ? a1 : a2)) + ko;
        const ushort* Bk = (s2 == 0 ? b0 : (s2 == 1 ? b1p : b2p)) + ko;
        ushort* buf = lds + pbuf * 16384;
        async16(Ak + eA0, buf + t * 8);
        async16(Ak + eA1, buf + (t + 512) * 8);
        async16(Bk + eB0, buf + 8192 + t * 8);
        async16(Bk + eB1, buf + 8192 + (t + 512) * 8);
    };

    const f32x4 zero = {0.f, 0.f, 0.f, 0.f};
    f32x4 acc[8][4];
#pragma unroll
    for (int i = 0; i < 8; ++i)
#pragma unroll
        for (int j = 0; j < 4; ++j) acc[i][j] = zero;

    const int aB = (wm + lr) * 32 + (lg ^ sw) * 8;          // elems
    const int bB = 8192 + (wn + lr) * 32 + (lg ^ sw) * 8;

    STAGE(0, 0);

    for (int kt = 0; kt < NTt; ++kt) {
        const int p = kt & 1;
        if (kt + 1 < NTt) {
            STAGE(kt + 1, p ^ 1);
            asm volatile("s_waitcnt vmcnt(4)" ::: "memory");  // own kt loads done
        } else {
            asm volatile("s_waitcnt vmcnt(0)" ::: "memory");
        }
        __builtin_amdgcn_s_barrier();          // buf[p] fully populated (all waves)
        asm volatile("" ::: "memory");
        __builtin_amdgcn_sched_barrier(0);

        const ushort* buf = lds + p * 16384;
#pragma unroll
        for (int ph = 0; ph < 4; ++ph) {
            const int mh = ph >> 1, nh = ph & 1;
            bf16x8 af[4], bfr[2];
#pragma unroll
            for (int i = 0; i < 4; ++i)
                af[i] = *(const bf16x8*)(buf + aB + (mh * 64 + i * 16) * 32);
#pragma unroll
            for (int j = 0; j < 2; ++j)
                bfr[j] = *(const bf16x8*)(buf + bB + (nh * 32 + j * 16) * 32);
            __builtin_amdgcn_s_setprio(1);
#pragma unroll
            for (int i = 0; i < 4; ++i)
#pragma unroll
                for (int j = 0; j < 2; ++j)
                    acc[mh * 4 + i][nh * 2 + j] = __builtin_amdgcn_mfma_f32_16x16x32_bf16(
                        af[i], bfr[j], acc[mh * 4 + i][nh * 2 + j], 0, 0, 0);
            __builtin_amdgcn_s_setprio(0);
        }
        asm volatile("" ::: "memory");
        __builtin_amdgcn_sched_barrier(0);
        __builtin_amdgcn_s_barrier();          // all reads of buf[p] done before
    }                                          // next iter stages kt+2 into it

    // epilogue: C/D frag mapping col = l&15, row = (l>>4)*4 + reg
    float*  Cfb = Cf  ? (Cf  + (long)bz * sCb) : nullptr;
    ushort* Chb = Chi ? (Chi + (long)bz * sCb) : nullptr;
    ushort* Clb = Clo ? (Clo + (long)bz * sCb) : nullptr;
#pragma unroll
    for (int j = 0; j < 4; ++j) {
        long n = n0 + wn + j * 16 + lr;
        float bv = 0.f;
        if (OUTMODE == 3) bv = bias[n];
        if (OUTMODE == 2) { if (bias) bv = bias[n]; }
#pragma unroll
        for (int i = 0; i < 8; ++i) {
            long mb = m0 + wm + i * 16 + lg * 4;
#pragma unroll
            for (int r = 0; r < 4; ++r) {
                float x = acc[i][j][r] + bv;
                long idx = (mb + r) * ldc + n;
                if (OUTMODE == 3) {
                    Cfb[idx] = tanhf(x);
                } else if (OUTMODE == 2) {
                    ushort h = f2bf(x);
                    Chb[idx] = h;
                    if (Clb) Clb[idx] = f2bf(x - bf2f(h));
                } else {
                    Cfb[idx] = x;
                }
            }
        }
    }
}

// ---------------------------------------------------------------------------
// Elementwise f32 -> (hi, lo) bf16 pair
// ---------------------------------------------------------------------------
__global__ __launch_bounds__(256) void split_pair_k(
    const float* __restrict__ in, ushort* __restrict__ hi, ushort* __restrict__ lo, long n4)
{
    long i = (long)blockIdx.x * 256 + threadIdx.x;
    const long stride = (long)gridDim.x * 256;
    for (; i < n4; i += stride) {
        float4 x = ((const float4*)in)[i];
        ushort4 h, lw;
        h.x = f2bf(x.x); lw.x = f2bf(x.x - bf2f(h.x));
        h.y = f2bf(x.y); lw.y = f2bf(x.y - bf2f(h.y));
        h.z = f2bf(x.z); lw.z = f2bf(x.z - bf2f(h.z));
        h.w = f2bf(x.w); lw.w = f2bf(x.w - bf2f(h.w));
        ((ushort4*)hi)[i] = h;
        ((ushort4*)lo)[i] = lw;
    }
}

// ---------------------------------------------------------------------------
// values [2048][32][1024] f32 -> per batch-group:
//   vhi/vlo [(s*gc+bi)][1024] bf16 pair  (K2 B-operand, NT)
//   vT [bi][1024][2048] bf16             (K4 B-operand, NT)
// ---------------------------------------------------------------------------
__global__ __launch_bounds__(256) void values_conv_k(
    const float* __restrict__ values,
    ushort* __restrict__ vhi, ushort* __restrict__ vlo, ushort* __restrict__ vT,
    int b0, int gc)
{
    __shared__ float tile[64][65];
    const int t  = threadIdx.x;
    const int s0 = blockIdx.x * 64;
    const int v0 = blockIdx.y * 64;
    const int bi = blockIdx.z;
    const int b  = b0 + bi;
#pragma unroll
    for (int i = 0; i < 4; ++i) {
        int c = t + i * 256;
        int r = c >> 4;
        int qq = c & 15;
        float4 x = *(const float4*)(values + ((long)(s0 + r) * 32 + b) * 1024 + v0 + qq * 4);
        ushort4 h, lw;
        h.x = f2bf(x.x); lw.x = f2bf(x.x - bf2f(h.x));
        h.y = f2bf(x.y); lw.y = f2bf(x.y - bf2f(h.y));
        h.z = f2bf(x.z); lw.z = f2bf(x.z - bf2f(h.z));
        h.w = f2bf(x.w); lw.w = f2bf(x.w - bf2f(h.w));
        long rowoff = ((long)(s0 + r) * gc + bi) * 1024 + v0 + qq * 4;
        *(ushort4*)(vhi + rowoff) = h;
        *(ushort4*)(vlo + rowoff) = lw;
        tile[r][qq * 4 + 0] = x.x;
        tile[r][qq * 4 + 1] = x.y;
        tile[r][qq * 4 + 2] = x.z;
        tile[r][qq * 4 + 3] = x.w;
    }
    __syncthreads();
    const int vr = t >> 2;
    const int ss = (t & 3) * 16;
    ushort* dst = vT + ((long)bi * 1024 + v0 + vr) * 2048 + s0 + ss;
#pragma unroll
    for (int j = 0; j < 4; ++j) {
        ushort4 o;
        o.x = f2bf(tile[ss + j * 4 + 0][vr]);
        o.y = f2bf(tile[ss + j * 4 + 1][vr]);
        o.z = f2bf(tile[ss + j * 4 + 2][vr]);
        o.w = f2bf(tile[ss + j * 4 + 3][vr]);
        *(ushort4*)(dst + j * 4) = o;
    }
}

// softmax over 2048-rows, f32 in -> bf16 P out. One 256-thread block per row.
__global__ __launch_bounds__(256) void softmax2048b_k(
    const float* __restrict__ S, ushort* __restrict__ P)
{
    __shared__ float red[4];
    const long row = blockIdx.x;
    const float* p = S + row * 2048 + threadIdx.x * 8;
    float4 a = ((const float4*)p)[0];
    float4 b = ((const float4*)p)[1];

    float m = fmaxf(fmaxf(fmaxf(a.x, a.y), fmaxf(a.z, a.w)),
                    fmaxf(fmaxf(b.x, b.y), fmaxf(b.z, b.w)));
#pragma unroll
    for (int off = 32; off; off >>= 1) m = fmaxf(m, __shfl_xor(m, off));
    int wid = threadIdx.x >> 6;
    if ((threadIdx.x & 63) == 0) red[wid] = m;
    __syncthreads();
    m = fmaxf(fmaxf(red[0], red[1]), fmaxf(red[2], red[3]));
    __syncthreads();

    a.x = __expf(a.x - m); a.y = __expf(a.y - m);
    a.z = __expf(a.z - m); a.w = __expf(a.w - m);
    b.x = __expf(b.x - m); b.y = __expf(b.y - m);
    b.z = __expf(b.z - m); b.w = __expf(b.w - m);

    float s = a.x + a.y + a.z + a.w + b.x + b.y + b.z + b.w;
#pragma unroll
    for (int off = 32; off; off >>= 1) s += __shfl_xor(s, off);
    if ((threadIdx.x & 63) == 0) red[wid] = s;
    __syncthreads();
    s = red[0] + red[1] + red[2] + red[3];
    float inv = 1.0f / s;

    ushort* qp = P + row * 2048 + threadIdx.x * 8;
    ushort4 oA, oB;
    oA.x = f2bf(a.x * inv); oA.y = f2bf(a.y * inv);
    oA.z = f2bf(a.z * inv); oA.w = f2bf(a.w * inv);
    oB.x = f2bf(b.x * inv); oB.y = f2bf(b.y * inv);
    oB.z = f2bf(b.z * inv); oB.w = f2bf(b.w * inv);
    ((ushort4*)qp)[0] = oA;
    ((ushort4*)qp)[1] = oB;
}

// ===========================================================================
// Fallback fp32 path (used only if ws_size is too small)
// ===========================================================================
#define BM 128
#define BN 128
#define BK 16

template<bool NT, int MODE>
__global__ __launch_bounds__(256) void gemm_f32(
    const float* __restrict__ A, const float* __restrict__ A2, int Ksplit,
    const float* __restrict__ Bm, const float* __restrict__ bias,
    float* __restrict__ C,
    long lda, long ldb, long ldc, int K,
    long sAb, long sBb, long sCb)
{
    __shared__ float As[BK][BM + 4];
    __shared__ float Bs[BK][BN + 4];

    const int bz = blockIdx.z;
    const float* Ab  = A + (long)bz * sAb;
    const float* A2b = A2 ? (A2 + (long)bz * sAb) : nullptr;
    const float* Bb  = Bm + (long)bz * sBb;
    float*       Cb  = C + (long)bz * sCb;

    const int m0 = blockIdx.y * BM;
    const int n0 = blockIdx.x * BN;
    const int t  = threadIdx.x;
    const int tx = t & 15;
    const int ty = t >> 4;

    float acc[8][8];
#pragma unroll
    for (int i = 0; i < 8; ++i)
#pragma unroll
        for (int j = 0; j < 8; ++j) acc[i][j] = 0.f;

    for (int k0 = 0; k0 < K; k0 += BK) {
        const float* Asrc = (A2b && k0 >= Ksplit) ? (A2b - Ksplit) : Ab;
#pragma unroll
        for (int c = 0; c < 2; ++c) {
            int chunk = t + c * 256;
            int row = chunk >> 2;
            int kq  = chunk & 3;
            float4 v = *(const float4*)(Asrc + (long)(m0 + row) * lda + k0 + kq * 4);
            As[kq * 4 + 0][row] = v.x;
            As[kq * 4 + 1][row] = v.y;
            As[kq * 4 + 2][row] = v.z;
            As[kq * 4 + 3][row] = v.w;
        }
        if (NT) {
#pragma unroll
            for (int c = 0; c < 2; ++c) {
                int chunk = t + c * 256;
                int row = chunk >> 2;
                int kq  = chunk & 3;
                float4 v = *(const float4*)(Bb + (long)(n0 + row) * ldb + k0 + kq * 4);
                Bs[kq * 4 + 0][row] = v.x;
                Bs[kq * 4 + 1][row] = v.y;
                Bs[kq * 4 + 2][row] = v.z;
                Bs[kq * 4 + 3][row] = v.w;
            }
        } else {
#pragma unroll
            for (int c = 0; c < 2; ++c) {
                int chunk = t + c * 256;
                int kr = chunk >> 5;
                int vq = chunk & 31;
                float4 v = *(const float4*)(Bb + (long)(k0 + kr) * ldb + n0 + vq * 4);
                *(float4*)&Bs[kr][vq * 4] = v;
            }
        }
        __syncthreads();

#pragma unroll
        for (int k = 0; k < BK; ++k) {
            float4 a0 = *(const float4*)&As[k][ty * 8];
            float4 a1 = *(const float4*)&As[k][ty * 8 + 4];
            float4 b0 = *(const float4*)&Bs[k][tx * 8];
            float4 b1 = *(const float4*)&Bs[k][tx * 8 + 4];
            float ar[8] = {a0.x, a0.y, a0.z, a0.w, a1.x, a1.y, a1.z, a1.w};
            float br[8] = {b0.x, b0.y, b0.z, b0.w, b1.x, b1.y, b1.z, b1.w};
#pragma unroll
            for (int i = 0; i < 8; ++i)
#pragma unroll
                for (int j = 0; j < 8; ++j)
                    acc[i][j] += ar[i] * br[j];
        }
        __syncthreads();
    }

    float brow[8];
    if (MODE >= 1) {
#pragma unroll
        for (int j = 0; j < 8; ++j) brow[j] = bias[n0 + tx * 8 + j];
    }
#pragma unroll
    for (int i = 0; i < 8; ++i) {
        long row = m0 + ty * 8 + i;
        float v[8];
#pragma unroll
        for (int j = 0; j < 8; ++j) {
            float x = acc[i][j];
            if (MODE >= 1) x += brow[j];
            if (MODE == 2) x = tanhf(x);
            v[j] = x;
        }
        float4* dst = (float4*)&Cb[row * ldc + n0 + tx * 8];
        dst[0] = make_float4(v[0], v[1], v[2], v[3]);
        dst[1] = make_float4(v[4], v[5], v[6], v[7]);
    }
}

__global__ __launch_bounds__(256) void softmax2048(float* __restrict__ S)
{
    __shared__ float red[4];
    float* p = S + (long)blockIdx.x * 2048 + threadIdx.x * 8;
    float4 a = ((float4*)p)[0];
    float4 b = ((float4*)p)[1];

    float m = fmaxf(fmaxf(fmaxf(a.x, a.y), fmaxf(a.z, a.w)),
                    fmaxf(fmaxf(b.x, b.y), fmaxf(b.z, b.w)));
#pragma unroll
    for (int off = 32; off; off >>= 1) m = fmaxf(m, __shfl_xor(m, off));
    int wid = threadIdx.x >> 6;
    if ((threadIdx.x & 63) == 0) red[wid] = m;
    __syncthreads();
    m = fmaxf(fmaxf(red[0], red[1]), fmaxf(red[2], red[3]));
    __syncthreads();

    a.x = __expf(a.x - m); a.y = __expf(a.y - m);
    a.z = __expf(a.z - m); a.w = __expf(a.w - m);
    b.x = __expf(b.x - m); b.y = __expf(b.y - m);
    b.z = __expf(b.z - m); b.w = __expf(b.w - m);

    float s = a.x + a.y + a.z + a.w + b.x + b.y + b.z + b.w;
#pragma unroll
    for (int off = 32; off; off >>= 1) s += __shfl_xor(s, off);
    if ((threadIdx.x & 63) == 0) red[wid] = s;
    __syncthreads();
    s = red[0] + red[1] + red[2] + red[3];
    float inv = 1.0f / s;

    a.x *= inv; a.y *= inv; a.z *= inv; a.w *= inv;
    b.x *= inv; b.y *= inv; b.z *= inv; b.w *= inv;
    ((float4*)p)[0] = a;
    ((float4*)p)[1] = b;
}

// ===========================================================================
extern "C" void kernel_launch(void* const* d_in, const int* in_sizes, int n_in,
                              void* d_out, int out_size, void* d_ws, size_t ws_size,
                              hipStream_t stream)
{
    const float* query  = (const float*)d_in[0];
    const float* values = (const float*)d_in[1];
    const float* W1     = (const float*)d_in[2];
    const float* b1     = (const float*)d_in[3];
    const float* W2     = (const float*)d_in[4];
    const float* b2     = (const float*)d_in[5];
    float* out = (float*)d_out;

    const int Bc = 32, QL = 512, SL = 2048, D = 1024, F = 2048;
    const long R = (long)QL * Bc;   // 16384

    char* p = (char*)d_ws;
    auto take = [&](size_t bytes) -> char* {
        char* r = p;
        p += (bytes + 255) & ~(size_t)255;
        return r;
    };

    ushort* q_hi  = (ushort*)take((size_t)R * D * 2);
    ushort* q_lo  = (ushort*)take((size_t)R * D * 2);
    ushort* w1_hi = (ushort*)take((size_t)D * D * 2);
    ushort* w1_lo = (ushort*)take((size_t)D * D * 2);
    ushort* w2_hi = (ushort*)take((size_t)D * F * 2);
    ushort* w2_lo = (ushort*)take((size_t)D * F * 2);
    ushort* qr_hi = (ushort*)take((size_t)R * D * 2);
    ushort* qr_lo = (ushort*)take((size_t)R * D * 2);
    ushort* at_hi = (ushort*)take((size_t)R * D * 2);
    size_t fixedBytes = (size_t)(p - (char*)d_ws);

    // per batch: vals hi+lo+vT (3 x 4 MB) + scores f32 (4 MB) + P bf16 (2 MB)
    const size_t perBatch = (size_t)SL * D * 2 * 3 + (size_t)QL * SL * 4 + (size_t)QL * SL * 2 + 2048;
    long availB = (long)ws_size - (long)fixedBytes;
    int g = availB > 0 ? (int)(availB / (long)perBatch) : 0;
    if (g > 32) g = 32;

    if (g >= 1) {
        // ----------------------- fast split-bf16 MFMA path -----------------
        ushort* vals_hi = (ushort*)take((size_t)SL * D * 2 * g);
        ushort* vals_lo = (ushort*)take((size_t)SL * D * 2 * g);
        ushort* vT      = (ushort*)take((size_t)SL * D * 2 * g);
        float*  scores  = (float*) take((size_t)QL * SL * 4 * g);
        ushort* P       = (ushort*)take((size_t)QL * SL * 2 * g);

        split_pair_k<<<2048, 256, 0, stream>>>(query, q_hi, q_lo, R * D / 4);
        split_pair_k<<<1024, 256, 0, stream>>>(W1, w1_hi, w1_lo, (long)D * D / 4);
        split_pair_k<<<1024, 256, 0, stream>>>(W2, w2_hi, w2_lo, (long)D * F / 4);

        // K1: qr = query.W1^T + b1  (3-term split) -> bf16 pair
        gemm256<2><<<dim3(D / 256, R / 256, 1), 512, 0, stream>>>(
            q_hi, q_hi, q_lo, w1_hi, w1_lo, w1_hi,
            D, D, 3, D, b1,
            nullptr, qr_hi, qr_lo,
            D, 0, 0, 0);

        for (int b0 = 0; b0 < Bc; b0 += g) {
            int gc = (Bc - b0 < g) ? (Bc - b0) : g;

            values_conv_k<<<dim3(SL / 64, D / 64, gc), 256, 0, stream>>>(
                values, vals_hi, vals_lo, vT, b0, gc);

            // K2: scores[bi,q,s] = qr . values  (3-term split) -> f32
            gemm256<0><<<dim3(SL / 256, QL / 256, gc), 512, 0, stream>>>(
                qr_hi + (size_t)b0 * D, qr_hi + (size_t)b0 * D, qr_lo + (size_t)b0 * D,
                vals_hi, vals_lo, vals_hi,
                (long)Bc * D, (long)gc * D, 3, D, nullptr,
                scores, nullptr, nullptr,
                SL, D, D, (long)QL * SL);

            softmax2048b_k<<<gc * QL, 256, 0, stream>>>(scores, P);

            // K4: att = P . vT  (1-term) -> bf16 hi
            gemm256<2><<<dim3(D / 256, QL / 256, gc), 512, 0, stream>>>(
                P, P, P, vT, vT, vT,
                SL, SL, 1, SL, nullptr,
                nullptr, at_hi + (size_t)b0 * D, nullptr,
                (long)Bc * D, (long)QL * SL, (long)D * SL, D);
        }

        // K5: out = tanh([att | query] . W2^T + b2)  (1-term, 2 K-segments)
        gemm256<3><<<dim3(D / 256, R / 256, 1), 512, 0, stream>>>(
            at_hi, q_hi, q_hi, w2_hi, w2_hi + 1024, w2_hi,
            D, F, 2, D, b2,
            out, nullptr, nullptr,
            D, 0, 0, 0);
        return;
    }

    // ----------------------- fp32 fallback ---------------------------------
    float* qr = (float*)d_ws;
    size_t qrBytes = (size_t)R * D * sizeof(float);
    float* sc = (float*)((char*)d_ws + qrBytes);
    size_t scPerB = (size_t)QL * SL * sizeof(float);

    int grp = 32;
    if (ws_size < qrBytes + 32 * scPerB) {
        size_t avail = ws_size > qrBytes ? ws_size - qrBytes : 0;
        grp = (int)(avail / scPerB);
        if (grp < 1)  grp = 1;
        if (grp > 32) grp = 32;
    }

    {
        dim3 gd(D / BN, R / BM, 1);
        gemm_f32<true, 1><<<gd, 256, 0, stream>>>(
            query, nullptr, 1 << 30, W1, b1, qr,
            D, D, D, D, 0, 0, 0);
    }
    for (int b0 = 0; b0 < Bc; b0 += grp) {
        int gg = (Bc - b0 < grp) ? (Bc - b0) : grp;
        {
            dim3 gd(SL / BN, QL / BM, gg);
            gemm_f32<true, 0><<<gd, 256, 0, stream>>>(
                qr + (size_t)b0 * D, nullptr, 1 << 30,
                values + (size_t)b0 * D, nullptr, sc,
                (long)Bc * D, (long)Bc * D, SL, D,
                D, D, (long)QL * SL);
        }
        softmax2048<<<gg * QL, 256, 0, stream>>>(sc);
        {
            dim3 gd(D / BN, QL / BM, gg);
            gemm_f32<false, 0><<<gd, 256, 0, stream>>>(
                sc, nullptr, 1 << 30,
                values + (size_t)b0 * D, nullptr, qr + (size_t)b0 * D,
                SL, (long)Bc * D, (long)Bc * D, SL,
                (long)QL * SL, D, D);
        }
    }
    {
        dim3 gd(D / BN, R / BM, 1);
        gemm_f32<true, 2><<<gd, 256, 0, stream>>>(
            qr, query, D, W2, b2, out,
            D, 2048, D, 2048, 0, 0, 0);
    }
}

// Round 4
// 842.726 us; speedup vs baseline: 1.5294x; 1.5294x over previous
//
#include <hip/hip_runtime.h>
#include <hip/hip_bf16.h>

// GlobalAttention: Q_LEN=512, SRC_LEN=2048, B=32, D=1024, F=2048
// Round 4: revert to round-2 proven 128x128 MFMA structure; K5 as 1-term
// concat-K GEMM (round-3-validated numerics), K4 hi-only output.
//   K1: qr = query.W1^T + b1           split(3-term), bf16-pair out
//   K2: scores[b,q,s] = qr . values    split(3-term), f32 out
//   SM: softmax rows -> P (bf16)
//   K4: att = P . vT                   1-term, bf16-hi out
//   K5: out = tanh([att|q].W2^T + b2)  1-term, concat at K=1024
// Fallback (ws too small): fp32 VALU pipeline.

typedef __attribute__((ext_vector_type(8))) short bf16x8;
typedef __attribute__((ext_vector_type(4))) float f32x4;

__device__ __forceinline__ ushort f2bf(float x) {
    unsigned u = __builtin_bit_cast(unsigned, x);
    u += 0x7FFFu + ((u >> 16) & 1u);
    return (ushort)(u >> 16);
}
__device__ __forceinline__ float bf2f(ushort h) {
    unsigned u = (unsigned)h << 16;
    return __builtin_bit_cast(float, u);
}

__device__ __forceinline__ void async16(const ushort* g, ushort* l) {
    __builtin_amdgcn_global_load_lds(
        (const __attribute__((address_space(1))) unsigned int*)g,
        (__attribute__((address_space(3))) unsigned int*)l, 16, 0, 0);
}

// ---------------------------------------------------------------------------
// MFMA GEMM: C[m,n] = sum_k A[m,k]*B[n,k]  (NT; all tiles K-contiguous rows)
// 128x128 tile, BK=32, 4 waves each 64x64 (4x4 frags of 16x16x32).
// SPLIT: A/B given as hi/lo bf16 pairs, 3-term accumulation.
// CONCAT: k >= Ksplit reads A2 (k-Ksplit), same lda.
// OUTMODE: 0=f32, 1=f32+bias, 2=bf16 hi (+lo if non-null) (+bias if non-null),
//          3=tanh(x+bias) f32
// LDS: linear [row][32] bf16 per tile, 16B-slot index XOR-swizzled by
// ((row>>1)&3) on BOTH the global source (staging) and the frag read.
// ---------------------------------------------------------------------------
template<bool SPLIT, bool CONCAT, int OUTMODE>
__global__ __launch_bounds__(256, 2) void gemm_bf16_mfma(
    const ushort* __restrict__ Ahi, const ushort* __restrict__ Alo,
    const ushort* __restrict__ A2hi, const ushort* __restrict__ A2lo, int Ksplit,
    const ushort* __restrict__ Bhi, const ushort* __restrict__ Blo,
    const float* __restrict__ bias,
    float* __restrict__ Cf, ushort* __restrict__ Chi, ushort* __restrict__ Clo,
    long lda, long ldb, long ldc, int K,
    long sAb, long sBb, long sCb)
{
    __shared__ ushort lds[(SPLIT ? 4 : 2) * 4096];
    ushort* sA0 = lds;
    ushort* sB0 = lds + 4096;
    ushort* sA1 = SPLIT ? (lds + 8192) : nullptr;
    ushort* sB1 = SPLIT ? (lds + 12288) : nullptr;

    const int t   = threadIdx.x;
    const int l   = t & 63;
    const int wid = t >> 6;
    const int wm  = (wid >> 1) * 64;
    const int wn  = (wid & 1) * 64;
    const int lr  = l & 15;
    const int lkp = ((l >> 4) ^ ((lr >> 1) & 3)) * 8;   // swizzled K-slot (elements)

    const long m0 = (long)blockIdx.y * 128;
    const long n0 = (long)blockIdx.x * 128;
    const int  bz = blockIdx.z;

    const ushort* Ah = Ahi + (long)bz * sAb;
    const ushort* Al = SPLIT ? (Alo + (long)bz * sAb) : nullptr;
    const ushort* Bh = Bhi + (long)bz * sBb;
    const ushort* Bl = SPLIT ? (Blo + (long)bz * sBb) : nullptr;

    // staging geometry: thread t covers chunks t (rows 0..63) and t+256 (rows 64..127)
    const int r0 = t >> 2, q = t & 3;
    const int qs = q ^ ((r0 >> 1) & 3);    // same for r0+64 since +64 keeps (r>>1)&3
    const long eA0 = (m0 + r0)      * lda + qs * 8;
    const long eA1 = (m0 + r0 + 64) * lda + qs * 8;
    const long eB0 = (n0 + r0)      * ldb + qs * 8;
    const long eB1 = (n0 + r0 + 64) * ldb + qs * 8;
    const int o0 = t * 8, o1 = (t + 256) * 8;

    const f32x4 zero = {0.f, 0.f, 0.f, 0.f};
    f32x4 acc[4][4];
#pragma unroll
    for (int i = 0; i < 4; ++i)
#pragma unroll
        for (int j = 0; j < 4; ++j) acc[i][j] = zero;

    for (int k0 = 0; k0 < K; k0 += 32) {
        const ushort *aHk, *aLk;
        if (CONCAT && k0 >= Ksplit) {
            aHk = A2hi + (k0 - Ksplit);
            aLk = SPLIT ? (A2lo + (k0 - Ksplit)) : nullptr;
        } else {
            aHk = Ah + k0;
            aLk = SPLIT ? (Al + k0) : nullptr;
        }
        const ushort* bHk = Bh + k0;
        const ushort* bLk = SPLIT ? (Bl + k0) : nullptr;

        async16(aHk + eA0, sA0 + o0);
        async16(aHk + eA1, sA0 + o1);
        async16(bHk + eB0, sB0 + o0);
        async16(bHk + eB1, sB0 + o1);
        if (SPLIT) {
            async16(aLk + eA0, sA1 + o0);
            async16(aLk + eA1, sA1 + o1);
            async16(bLk + eB0, sB1 + o0);
            async16(bLk + eB1, sB1 + o1);
        }
        __syncthreads();   // compiler emits vmcnt(0) drain before barrier

        bf16x8 ah[4], bh[4], al[4], bl[4];
#pragma unroll
        for (int mb = 0; mb < 4; ++mb) {
            int off = (wm + mb * 16 + lr) * 32 + lkp;
            ah[mb] = *(const bf16x8*)(sA0 + off);
            if (SPLIT) al[mb] = *(const bf16x8*)(sA1 + off);
        }
#pragma unroll
        for (int nb = 0; nb < 4; ++nb) {
            int off = (wn + nb * 16 + lr) * 32 + lkp;
            bh[nb] = *(const bf16x8*)(sB0 + off);
            if (SPLIT) bl[nb] = *(const bf16x8*)(sB1 + off);
        }
#pragma unroll
        for (int mb = 0; mb < 4; ++mb)
#pragma unroll
            for (int nb = 0; nb < 4; ++nb) {
                acc[mb][nb] = __builtin_amdgcn_mfma_f32_16x16x32_bf16(ah[mb], bh[nb], acc[mb][nb], 0, 0, 0);
                if (SPLIT) {
                    acc[mb][nb] = __builtin_amdgcn_mfma_f32_16x16x32_bf16(ah[mb], bl[nb], acc[mb][nb], 0, 0, 0);
                    acc[mb][nb] = __builtin_amdgcn_mfma_f32_16x16x32_bf16(al[mb], bh[nb], acc[mb][nb], 0, 0, 0);
                }
            }
        __syncthreads();
    }

    // epilogue: C/D frag mapping col = l&15, row = (l>>4)*4 + reg  [m89-verified]
    float*  Cfb = Cf  ? (Cf  + (long)bz * sCb) : nullptr;
    ushort* Chb = Chi ? (Chi + (long)bz * sCb) : nullptr;
    ushort* Clb = Clo ? (Clo + (long)bz * sCb) : nullptr;
    const int mrow = (l >> 4) * 4;
#pragma unroll
    for (int nb = 0; nb < 4; ++nb) {
        long n = n0 + wn + nb * 16 + lr;
        float bv = 0.f;
        if (OUTMODE == 1 || OUTMODE == 3) bv = bias[n];
        if (OUTMODE == 2) { if (bias) bv = bias[n]; }
#pragma unroll
        for (int mb = 0; mb < 4; ++mb) {
            long mbase = m0 + wm + mb * 16 + mrow;
#pragma unroll
            for (int r = 0; r < 4; ++r) {
                float x = acc[mb][nb][r] + bv;
                long idx = (mbase + r) * ldc + n;
                if (OUTMODE == 3) {
                    Cfb[idx] = tanhf(x);
                } else if (OUTMODE == 2) {
                    ushort h = f2bf(x);
                    Chb[idx] = h;
                    if (Clb) Clb[idx] = f2bf(x - bf2f(h));
                } else {
                    Cfb[idx] = x;
                }
            }
        }
    }
}

// ---------------------------------------------------------------------------
// Elementwise f32 -> (hi, lo) bf16 pair
// ---------------------------------------------------------------------------
__global__ __launch_bounds__(256) void split_pair_k(
    const float* __restrict__ in, ushort* __restrict__ hi, ushort* __restrict__ lo, long n4)
{
    long i = (long)blockIdx.x * 256 + threadIdx.x;
    const long stride = (long)gridDim.x * 256;
    for (; i < n4; i += stride) {
        float4 x = ((const float4*)in)[i];
        ushort4 h, lw;
        h.x = f2bf(x.x); lw.x = f2bf(x.x - bf2f(h.x));
        h.y = f2bf(x.y); lw.y = f2bf(x.y - bf2f(h.y));
        h.z = f2bf(x.z); lw.z = f2bf(x.z - bf2f(h.z));
        h.w = f2bf(x.w); lw.w = f2bf(x.w - bf2f(h.w));
        ((ushort4*)hi)[i] = h;
        ((ushort4*)lo)[i] = lw;
    }
}

// ---------------------------------------------------------------------------
// values [2048][32][1024] f32 -> per batch-group:
//   vhi/vlo [(s*gc+bi)][1024] bf16 pair  (K2 B-operand, NT)
//   vT [bi][1024][2048] bf16             (K4 B-operand, NT)
// ---------------------------------------------------------------------------
__global__ __launch_bounds__(256) void values_conv_k(
    const float* __restrict__ values,
    ushort* __restrict__ vhi, ushort* __restrict__ vlo, ushort* __restrict__ vT,
    int b0, int gc)
{
    __shared__ float tile[64][65];
    const int t  = threadIdx.x;
    const int s0 = blockIdx.x * 64;
    const int v0 = blockIdx.y * 64;
    const int bi = blockIdx.z;
    const int b  = b0 + bi;
#pragma unroll
    for (int i = 0; i < 4; ++i) {
        int c = t + i * 256;
        int r = c >> 4;
        int qq = c & 15;
        float4 x = *(const float4*)(values + ((long)(s0 + r) * 32 + b) * 1024 + v0 + qq * 4);
        ushort4 h, lw;
        h.x = f2bf(x.x); lw.x = f2bf(x.x - bf2f(h.x));
        h.y = f2bf(x.y); lw.y = f2bf(x.y - bf2f(h.y));
        h.z = f2bf(x.z); lw.z = f2bf(x.z - bf2f(h.z));
        h.w = f2bf(x.w); lw.w = f2bf(x.w - bf2f(h.w));
        long rowoff = ((long)(s0 + r) * gc + bi) * 1024 + v0 + qq * 4;
        *(ushort4*)(vhi + rowoff) = h;
        *(ushort4*)(vlo + rowoff) = lw;
        tile[r][qq * 4 + 0] = x.x;
        tile[r][qq * 4 + 1] = x.y;
        tile[r][qq * 4 + 2] = x.z;
        tile[r][qq * 4 + 3] = x.w;
    }
    __syncthreads();
    const int vr = t >> 2;
    const int ss = (t & 3) * 16;
    ushort* dst = vT + ((long)bi * 1024 + v0 + vr) * 2048 + s0 + ss;
#pragma unroll
    for (int j = 0; j < 4; ++j) {
        ushort4 o;
        o.x = f2bf(tile[ss + j * 4 + 0][vr]);
        o.y = f2bf(tile[ss + j * 4 + 1][vr]);
        o.z = f2bf(tile[ss + j * 4 + 2][vr]);
        o.w = f2bf(tile[ss + j * 4 + 3][vr]);
        *(ushort4*)(dst + j * 4) = o;
    }
}

// softmax over 2048-rows, f32 in -> bf16 P out. One 256-thread block per row.
__global__ __launch_bounds__(256) void softmax2048b_k(
    const float* __restrict__ S, ushort* __restrict__ P)
{
    __shared__ float red[4];
    const long row = blockIdx.x;
    const float* p = S + row * 2048 + threadIdx.x * 8;
    float4 a = ((const float4*)p)[0];
    float4 b = ((const float4*)p)[1];

    float m = fmaxf(fmaxf(fmaxf(a.x, a.y), fmaxf(a.z, a.w)),
                    fmaxf(fmaxf(b.x, b.y), fmaxf(b.z, b.w)));
#pragma unroll
    for (int off = 32; off; off >>= 1) m = fmaxf(m, __shfl_xor(m, off));
    int wid = threadIdx.x >> 6;
    if ((threadIdx.x & 63) == 0) red[wid] = m;
    __syncthreads();
    m = fmaxf(fmaxf(red[0], red[1]), fmaxf(red[2], red[3]));
    __syncthreads();

    a.x = __expf(a.x - m); a.y = __expf(a.y - m);
    a.z = __expf(a.z - m); a.w = __expf(a.w - m);
    b.x = __expf(b.x - m); b.y = __expf(b.y - m);
    b.z = __expf(b.z - m); b.w = __expf(b.w - m);

    float s = a.x + a.y + a.z + a.w + b.x + b.y + b.z + b.w;
#pragma unroll
    for (int off = 32; off; off >>= 1) s += __shfl_xor(s, off);
    if ((threadIdx.x & 63) == 0) red[wid] = s;
    __syncthreads();
    s = red[0] + red[1] + red[2] + red[3];
    float inv = 1.0f / s;

    ushort* qp = P + row * 2048 + threadIdx.x * 8;
    ushort4 oA, oB;
    oA.x = f2bf(a.x * inv); oA.y = f2bf(a.y * inv);
    oA.z = f2bf(a.z * inv); oA.w = f2bf(a.w * inv);
    oB.x = f2bf(b.x * inv); oB.y = f2bf(b.y * inv);
    oB.z = f2bf(b.z * inv); oB.w = f2bf(b.w * inv);
    ((ushort4*)qp)[0] = oA;
    ((ushort4*)qp)[1] = oB;
}

// ===========================================================================
// Fallback fp32 path (used only if ws_size is too small)
// ===========================================================================
#define BM 128
#define BN 128
#define BK 16

template<bool NT, int MODE>
__global__ __launch_bounds__(256) void gemm_f32(
    const float* __restrict__ A, const float* __restrict__ A2, int Ksplit,
    const float* __restrict__ Bm, const float* __restrict__ bias,
    float* __restrict__ C,
    long lda, long ldb, long ldc, int K,
    long sAb, long sBb, long sCb)
{
    __shared__ float As[BK][BM + 4];
    __shared__ float Bs[BK][BN + 4];

    const int bz = blockIdx.z;
    const float* Ab  = A + (long)bz * sAb;
    const float* A2b = A2 ? (A2 + (long)bz * sAb) : nullptr;
    const float* Bb  = Bm + (long)bz * sBb;
    float*       Cb  = C + (long)bz * sCb;

    const int m0 = blockIdx.y * BM;
    const int n0 = blockIdx.x * BN;
    const int t  = threadIdx.x;
    const int tx = t & 15;
    const int ty = t >> 4;

    float acc[8][8];
#pragma unroll
    for (int i = 0; i < 8; ++i)
#pragma unroll
        for (int j = 0; j < 8; ++j) acc[i][j] = 0.f;

    for (int k0 = 0; k0 < K; k0 += BK) {
        const float* Asrc = (A2b && k0 >= Ksplit) ? (A2b - Ksplit) : Ab;
#pragma unroll
        for (int c = 0; c < 2; ++c) {
            int chunk = t + c * 256;
            int row = chunk >> 2;
            int kq  = chunk & 3;
            float4 v = *(const float4*)(Asrc + (long)(m0 + row) * lda + k0 + kq * 4);
            As[kq * 4 + 0][row] = v.x;
            As[kq * 4 + 1][row] = v.y;
            As[kq * 4 + 2][row] = v.z;
            As[kq * 4 + 3][row] = v.w;
        }
        if (NT) {
#pragma unroll
            for (int c = 0; c < 2; ++c) {
                int chunk = t + c * 256;
                int row = chunk >> 2;
                int kq  = chunk & 3;
                float4 v = *(const float4*)(Bb + (long)(n0 + row) * ldb + k0 + kq * 4);
                Bs[kq * 4 + 0][row] = v.x;
                Bs[kq * 4 + 1][row] = v.y;
                Bs[kq * 4 + 2][row] = v.z;
                Bs[kq * 4 + 3][row] = v.w;
            }
        } else {
#pragma unroll
            for (int c = 0; c < 2; ++c) {
                int chunk = t + c * 256;
                int kr = chunk >> 5;
                int vq = chunk & 31;
                float4 v = *(const float4*)(Bb + (long)(k0 + kr) * ldb + n0 + vq * 4);
                *(float4*)&Bs[kr][vq * 4] = v;
            }
        }
        __syncthreads();

#pragma unroll
        for (int k = 0; k < BK; ++k) {
            float4 a0 = *(const float4*)&As[k][ty * 8];
            float4 a1 = *(const float4*)&As[k][ty * 8 + 4];
            float4 b0 = *(const float4*)&Bs[k][tx * 8];
            float4 b1 = *(const float4*)&Bs[k][tx * 8 + 4];
            float ar[8] = {a0.x, a0.y, a0.z, a0.w, a1.x, a1.y, a1.z, a1.w};
            float br[8] = {b0.x, b0.y, b0.z, b0.w, b1.x, b1.y, b1.z, b1.w};
#pragma unroll
            for (int i = 0; i < 8; ++i)
#pragma unroll
                for (int j = 0; j < 8; ++j)
                    acc[i][j] += ar[i] * br[j];
        }
        __syncthreads();
    }

    float brow[8];
    if (MODE >= 1) {
#pragma unroll
        for (int j = 0; j < 8; ++j) brow[j] = bias[n0 + tx * 8 + j];
    }
#pragma unroll
    for (int i = 0; i < 8; ++i) {
        long row = m0 + ty * 8 + i;
        float v[8];
#pragma unroll
        for (int j = 0; j < 8; ++j) {
            float x = acc[i][j];
            if (MODE >= 1) x += brow[j];
            if (MODE == 2) x = tanhf(x);
            v[j] = x;
        }
        float4* dst = (float4*)&Cb[row * ldc + n0 + tx * 8];
        dst[0] = make_float4(v[0], v[1], v[2], v[3]);
        dst[1] = make_float4(v[4], v[5], v[6], v[7]);
    }
}

__global__ __launch_bounds__(256) void softmax2048(float* __restrict__ S)
{
    __shared__ float red[4];
    float* p = S + (long)blockIdx.x * 2048 + threadIdx.x * 8;
    float4 a = ((float4*)p)[0];
    float4 b = ((float4*)p)[1];

    float m = fmaxf(fmaxf(fmaxf(a.x, a.y), fmaxf(a.z, a.w)),
                    fmaxf(fmaxf(b.x, b.y), fmaxf(b.z, b.w)));
#pragma unroll
    for (int off = 32; off; off >>= 1) m = fmaxf(m, __shfl_xor(m, off));
    int wid = threadIdx.x >> 6;
    if ((threadIdx.x & 63) == 0) red[wid] = m;
    __syncthreads();
    m = fmaxf(fmaxf(red[0], red[1]), fmaxf(red[2], red[3]));
    __syncthreads();

    a.x = __expf(a.x - m); a.y = __expf(a.y - m);
    a.z = __expf(a.z - m); a.w = __expf(a.w - m);
    b.x = __expf(b.x - m); b.y = __expf(b.y - m);
    b.z = __expf(b.z - m); b.w = __expf(b.w - m);

    float s = a.x + a.y + a.z + a.w + b.x + b.y + b.z + b.w;
#pragma unroll
    for (int off = 32; off; off >>= 1) s += __shfl_xor(s, off);
    if ((threadIdx.x & 63) == 0) red[wid] = s;
    __syncthreads();
    s = red[0] + red[1] + red[2] + red[3];
    float inv = 1.0f / s;

    a.x *= inv; a.y *= inv; a.z *= inv; a.w *= inv;
    b.x *= inv; b.y *= inv; b.z *= inv; b.w *= inv;
    ((float4*)p)[0] = a;
    ((float4*)p)[1] = b;
}

// ===========================================================================
extern "C" void kernel_launch(void* const* d_in, const int* in_sizes, int n_in,
                              void* d_out, int out_size, void* d_ws, size_t ws_size,
                              hipStream_t stream)
{
    const float* query  = (const float*)d_in[0];
    const float* values = (const float*)d_in[1];
    const float* W1     = (const float*)d_in[2];
    const float* b1     = (const float*)d_in[3];
    const float* W2     = (const float*)d_in[4];
    const float* b2     = (const float*)d_in[5];
    float* out = (float*)d_out;

    const int Bc = 32, QL = 512, SL = 2048, D = 1024, F = 2048;
    const long R = (long)QL * Bc;   // 16384

    char* p = (char*)d_ws;
    auto take = [&](size_t bytes) -> char* {
        char* r = p;
        p += (bytes + 255) & ~(size_t)255;
        return r;
    };

    ushort* q_hi  = (ushort*)take((size_t)R * D * 2);
    ushort* q_lo  = (ushort*)take((size_t)R * D * 2);
    ushort* w1_hi = (ushort*)take((size_t)D * D * 2);
    ushort* w1_lo = (ushort*)take((size_t)D * D * 2);
    ushort* w2_hi = (ushort*)take((size_t)D * F * 2);
    ushort* w2_lo = (ushort*)take((size_t)D * F * 2);
    ushort* qr_hi = (ushort*)take((size_t)R * D * 2);
    ushort* qr_lo = (ushort*)take((size_t)R * D * 2);
    ushort* at_hi = (ushort*)take((size_t)R * D * 2);
    size_t fixedBytes = (size_t)(p - (char*)d_ws);

    // per batch: vals hi+lo+vT (3 * 4 MB) + scores f32 (4 MB) + P bf16 (2 MB)
    const size_t perBatch = (size_t)SL * D * 2 * 3 + (size_t)QL * SL * 4 + (size_t)QL * SL * 2 + 2048;
    long availB = (long)ws_size - (long)fixedBytes;
    int g = availB > 0 ? (int)(availB / (long)perBatch) : 0;
    if (g > 32) g = 32;

    if (g >= 1) {
        // ----------------------- fast split-bf16 MFMA path -----------------
        ushort* vals_hi = (ushort*)take((size_t)SL * D * 2 * g);
        ushort* vals_lo = (ushort*)take((size_t)SL * D * 2 * g);
        ushort* vT      = (ushort*)take((size_t)SL * D * 2 * g);
        float*  scores  = (float*) take((size_t)QL * SL * 4 * g);
        ushort* P       = (ushort*)take((size_t)QL * SL * 2 * g);

        split_pair_k<<<2048, 256, 0, stream>>>(query, q_hi, q_lo, R * D / 4);
        split_pair_k<<<1024, 256, 0, stream>>>(W1, w1_hi, w1_lo, (long)D * D / 4);
        split_pair_k<<<1024, 256, 0, stream>>>(W2, w2_hi, w2_lo, (long)D * F / 4);

        // K1: qr = query.W1^T + b1   (3-term split) -> bf16 pair
        gemm_bf16_mfma<true, false, 2><<<dim3(D / 128, R / 128, 1), 256, 0, stream>>>(
            q_hi, q_lo, nullptr, nullptr, 1 << 30,
            w1_hi, w1_lo, b1,
            nullptr, qr_hi, qr_lo,
            D, D, D, D, 0, 0, 0);

        for (int b0 = 0; b0 < Bc; b0 += g) {
            int gc = (Bc - b0 < g) ? (Bc - b0) : g;

            values_conv_k<<<dim3(SL / 64, D / 64, gc), 256, 0, stream>>>(
                values, vals_hi, vals_lo, vT, b0, gc);

            // K2: scores[bi,q,s] = qr[q*32+b,:] . values[s*32+b,:]  (3-term)
            gemm_bf16_mfma<true, false, 0><<<dim3(SL / 128, QL / 128, gc), 256, 0, stream>>>(
                qr_hi + (size_t)b0 * D, qr_lo + (size_t)b0 * D, nullptr, nullptr, 1 << 30,
                vals_hi, vals_lo, nullptr,
                scores, nullptr, nullptr,
                (long)Bc * D, (long)gc * D, SL, D,
                D, D, (long)QL * SL);

            softmax2048b_k<<<gc * QL, 256, 0, stream>>>(scores, P);

            // K4: att[q*32+b, v] = sum_s P[bi,q,s] * vT[bi,v,s]   -> bf16 hi only
            gemm_bf16_mfma<false, false, 2><<<dim3(D / 128, QL / 128, gc), 256, 0, stream>>>(
                P, nullptr, nullptr, nullptr, 1 << 30,
                vT, nullptr, nullptr,
                nullptr, at_hi + (size_t)b0 * D, nullptr,
                SL, SL, (long)Bc * D, SL,
                (long)QL * SL, (long)D * SL, D);
        }

        // K5: out = tanh([att | query] . W2^T + b2)  (1-term, concat at k=1024)
        gemm_bf16_mfma<false, true, 3><<<dim3(D / 128, R / 128, 1), 256, 0, stream>>>(
            at_hi, nullptr, q_hi, nullptr, D,
            w2_hi, nullptr, b2,
            out, nullptr, nullptr,
            D, F, D, F, 0, 0, 0);
        return;
    }

    // ----------------------- fp32 fallback ---------------------------------
    float* qr = (float*)d_ws;
    size_t qrBytes = (size_t)R * D * sizeof(float);
    float* sc = (float*)((char*)d_ws + qrBytes);
    size_t scPerB = (size_t)QL * SL * sizeof(float);

    int grp = 32;
    if (ws_size < qrBytes + 32 * scPerB) {
        size_t avail = ws_size > qrBytes ? ws_size - qrBytes : 0;
        grp = (int)(avail / scPerB);
        if (grp < 1)  grp = 1;
        if (grp > 32) grp = 32;
    }

    {
        dim3 gd(D / BN, R / BM, 1);
        gemm_f32<true, 1><<<gd, 256, 0, stream>>>(
            query, nullptr, 1 << 30, W1, b1, qr,
            D, D, D, D, 0, 0, 0);
    }
    for (int b0 = 0; b0 < Bc; b0 += grp) {
        int gg = (Bc - b0 < grp) ? (Bc - b0) : grp;
        {
            dim3 gd(SL / BN, QL / BM, gg);
            gemm_f32<true, 0><<<gd, 256, 0, stream>>>(
                qr + (size_t)b0 * D, nullptr, 1 << 30,
                values + (size_t)b0 * D, nullptr, sc,
                (long)Bc * D, (long)Bc * D, SL, D,
                D, D, (long)QL * SL);
        }
        softmax2048<<<gg * QL, 256, 0, stream>>>(sc);
        {
            dim3 gd(D / BN, QL / BM, gg);
            gemm_f32<false, 0><<<gd, 256, 0, stream>>>(
                sc, nullptr, 1 << 30,
                values + (size_t)b0 * D, nullptr, qr + (size_t)b0 * D,
                SL, (long)Bc * D, (long)Bc * D, SL,
                (long)QL * SL, D, D);
        }
    }
    {
        dim3 gd(D / BN, R / BM, 1);
        gemm_f32<true, 2><<<gd, 256, 0, stream>>>(
            qr, query, D, W2, b2, out,
            D, 2048, D, 2048, 0, 0, 0);
    }
}

// Round 5
// 705.851 us; speedup vs baseline: 1.8260x; 1.1939x over previous
//
#include <hip/hip_runtime.h>
#include <hip/hip_bf16.h>

// GlobalAttention: Q_LEN=512, SRC_LEN=2048, B=32, D=1024, F=2048
// Round 5: 256x256 / BK=32 / 32x32x16-MFMA GEMM with 4-deep LDS pipeline,
// counted vmcnt (loads issued 3 iters ahead), single barrier/iter, setprio,
// slot-XOR swizzle (round-2-proven), XCD block swizzle. Numerics = round 4.
//   K1: qr = query.W1^T + b1           3-term split segments, bf16-pair out
//   K2: scores = qr . values           3-term split segments, f32 out
//   SM: softmax -> P bf16
//   K4: att = P . vT                   1-term, bf16-hi out
//   K5: out = tanh([att|q].W2^T + b2)  1-term, 2 K-segments
// Fallback (ws too small): fp32 VALU pipeline.

typedef __attribute__((ext_vector_type(8)))  short bf16x8;
typedef __attribute__((ext_vector_type(4)))  float f32x4;
typedef __attribute__((ext_vector_type(16))) float f32x16;

__device__ __forceinline__ ushort f2bf(float x) {
    unsigned u = __builtin_bit_cast(unsigned, x);
    u += 0x7FFFu + ((u >> 16) & 1u);
    return (ushort)(u >> 16);
}
__device__ __forceinline__ float bf2f(ushort h) {
    unsigned u = (unsigned)h << 16;
    return __builtin_bit_cast(float, u);
}
__device__ __forceinline__ void async16(const ushort* g, ushort* l) {
    __builtin_amdgcn_global_load_lds(
        (const __attribute__((address_space(1))) unsigned int*)g,
        (__attribute__((address_space(3))) unsigned int*)l, 16, 0, 0);
}

// ---------------------------------------------------------------------------
// gemm256p: C[m,n] = sum_{seg} sum_k A_s[m*lda+k]*B_s[n*ldb+k]  (NT, segments)
// 256x256 tile, BK=32, 512 thr (8 waves 2Mx4N, wave tile 128x64 = 4x2 frags
// of 32x32x16). LDS: 4 pipeline buffers x (A 16KB + B 16KB... A 8192 elems +
// B 8192 elems) = 128 KiB total.
// Pipeline: prologue stages tiles 0,1,2. Iter t: vmcnt(8) [own t-loads done]
// -> s_barrier [all waves' t-loads done] -> STAGE(t+3 -> buf[(t+3)&3]) ->
// compute buf[t&3]. Tail iters use vmcnt(4)/vmcnt(0).
// Swizzle: 16B-slot index XORed with ((row>>1)&3) on BOTH stage-source and
// ds_read (0-conflict, round-2-proven).
// OUTMODE: 0=f32, 2=bf16 hi (+lo if non-null)(+bias if non-null), 3=tanh(x+bias)
// ---------------------------------------------------------------------------
template<int OUTMODE>
__global__ __launch_bounds__(512, 2) void gemm256p(
    const ushort* __restrict__ A0, const ushort* __restrict__ A1, const ushort* __restrict__ A2,
    const ushort* __restrict__ B0, const ushort* __restrict__ B1, const ushort* __restrict__ B2,
    long lda, long ldb, int tps, int nseg,
    const float* __restrict__ bias,
    float* __restrict__ Cf, ushort* __restrict__ Chi, ushort* __restrict__ Clo,
    long ldc, long sAb, long sBb, long sCb)
{
    __shared__ ushort lds[4][16384];   // 4 bufs x 32 KiB = 128 KiB

    const int t   = threadIdx.x;
    const int l   = t & 63;
    const int wid = t >> 6;
    const int lr  = l & 31;
    const int lg  = l >> 5;
    const int sw  = (lr >> 1) & 3;
    const int wm  = (wid >> 2) * 128;
    const int wn  = (wid & 3) * 64;

    // XCD-aware bijective block swizzle (all our grids have nwg % 8 == 0)
    const int gx = gridDim.x, gy = gridDim.y;
    const int nwg = gx * gy * gridDim.z;
    int w = ((int)blockIdx.z * gy + (int)blockIdx.y) * gx + (int)blockIdx.x;
    w = (w & 7) * (nwg >> 3) + (w >> 3);
    const int bx = w % gx;
    const int by = (w / gx) % gy;
    const int bz = w / (gx * gy);

    const long m0 = (long)by * 256;
    const long n0 = (long)bx * 256;

    const ushort* Asg[3] = { A0 + (long)bz * sAb, A1 + (long)bz * sAb, A2 + (long)bz * sAb };
    const ushort* Bsg[3] = { B0 + (long)bz * sBb, B1 + (long)bz * sBb, B2 + (long)bz * sBb };
    const int NTt = nseg * tps;

    // staging geometry: chunk c (0..1023 per operand tile): row=c>>2, slot=c&3
    // thread t covers chunks t and t+512 (row + 128). swizzled source slot.
    const int  rA = t >> 2, cA = t & 3;
    const long offA0 = (m0 + rA) * lda + (long)((cA ^ ((rA >> 1) & 3)) * 8);
    const long offA1 = offA0 + 128 * lda;
    const long offB0 = (n0 + rA) * ldb + (long)((cA ^ ((rA >> 1) & 3)) * 8);
    const long offB1 = offB0 + 128 * ldb;
    const int  dst0 = t * 8, dst1 = (t + 512) * 8;

    auto STAGE = [&](int kt, int buf) {
        int s2 = (kt >= tps) + (kt >= 2 * tps);
        long ko = (long)(kt - s2 * tps) * 32;
        const ushort* Ak = Asg[s2] + ko;
        const ushort* Bk = Bsg[s2] + ko;
        ushort* dA = &lds[buf][0];
        ushort* dB = &lds[buf][8192];
        async16(Ak + offA0, dA + dst0);
        async16(Ak + offA1, dA + dst1);
        async16(Bk + offB0, dB + dst0);
        async16(Bk + offB1, dB + dst1);
    };

    f32x16 acc[4][2];
#pragma unroll
    for (int mi = 0; mi < 4; ++mi)
#pragma unroll
        for (int nj = 0; nj < 2; ++nj)
#pragma unroll
            for (int r = 0; r < 16; ++r) acc[mi][nj][r] = 0.f;

    STAGE(0, 0);
    STAGE(1, 1);
    STAGE(2, 2);

    for (int kt = 0; kt < NTt; ++kt) {
        // per-wave counted wait: own tile-kt loads complete
        if (kt < NTt - 2)       asm volatile("s_waitcnt vmcnt(8)" ::: "memory");
        else if (kt == NTt - 2) asm volatile("s_waitcnt vmcnt(4)" ::: "memory");
        else                    asm volatile("s_waitcnt vmcnt(0)" ::: "memory");
        __builtin_amdgcn_sched_barrier(0);
        __builtin_amdgcn_s_barrier();        // all waves' tile-kt loads done;
        __builtin_amdgcn_sched_barrier(0);   // also closes iter kt-1's reads
        asm volatile("" ::: "memory");

        if (kt + 3 < NTt) STAGE(kt + 3, (kt + 3) & 3);   // writes buf[(kt-1)&3]

        const ushort* bufA = &lds[kt & 3][0];
        const ushort* bufB = &lds[kt & 3][8192];
#pragma unroll
        for (int ks = 0; ks < 2; ++ks) {
            bf16x8 af[4], bfr[2];
#pragma unroll
            for (int mi = 0; mi < 4; ++mi)
                af[mi] = *(const bf16x8*)(bufA + (wm + mi * 32 + lr) * 32 + (((ks * 2 + lg) ^ sw) * 8));
#pragma unroll
            for (int nj = 0; nj < 2; ++nj)
                bfr[nj] = *(const bf16x8*)(bufB + (wn + nj * 32 + lr) * 32 + (((ks * 2 + lg) ^ sw) * 8));
            __builtin_amdgcn_s_setprio(1);
#pragma unroll
            for (int mi = 0; mi < 4; ++mi)
#pragma unroll
                for (int nj = 0; nj < 2; ++nj)
                    acc[mi][nj] = __builtin_amdgcn_mfma_f32_32x32x16_bf16(
                        af[mi], bfr[nj], acc[mi][nj], 0, 0, 0);
            __builtin_amdgcn_s_setprio(0);
        }
    }

    // epilogue: 32x32 C/D mapping col = l&31, row = (reg&3)+8*(reg>>2)+4*(l>>5)
    float*  Cfb = Cf  ? (Cf  + (long)bz * sCb) : nullptr;
    ushort* Chb = Chi ? (Chi + (long)bz * sCb) : nullptr;
    ushort* Clb = Clo ? (Clo + (long)bz * sCb) : nullptr;
#pragma unroll
    for (int nj = 0; nj < 2; ++nj) {
        long ncol = n0 + wn + nj * 32 + lr;
        float bv = 0.f;
        if (OUTMODE == 3) bv = bias[ncol];
        if (OUTMODE == 2) { if (bias) bv = bias[ncol]; }
#pragma unroll
        for (int mi = 0; mi < 4; ++mi) {
            long mbase = m0 + wm + mi * 32 + 4 * lg;
#pragma unroll
            for (int r = 0; r < 16; ++r) {
                long row = mbase + (r & 3) + 8 * (r >> 2);
                float x = acc[mi][nj][r] + bv;
                long idx = row * ldc + ncol;
                if (OUTMODE == 3) {
                    Cfb[idx] = tanhf(x);
                } else if (OUTMODE == 2) {
                    ushort h = f2bf(x);
                    Chb[idx] = h;
                    if (Clb) Clb[idx] = f2bf(x - bf2f(h));
                } else {
                    Cfb[idx] = x;
                }
            }
        }
    }
}

// ---------------------------------------------------------------------------
// Elementwise f32 -> (hi, lo) bf16 pair
// ---------------------------------------------------------------------------
__global__ __launch_bounds__(256) void split_pair_k(
    const float* __restrict__ in, ushort* __restrict__ hi, ushort* __restrict__ lo, long n4)
{
    long i = (long)blockIdx.x * 256 + threadIdx.x;
    const long stride = (long)gridDim.x * 256;
    for (; i < n4; i += stride) {
        float4 x = ((const float4*)in)[i];
        ushort4 h, lw;
        h.x = f2bf(x.x); lw.x = f2bf(x.x - bf2f(h.x));
        h.y = f2bf(x.y); lw.y = f2bf(x.y - bf2f(h.y));
        h.z = f2bf(x.z); lw.z = f2bf(x.z - bf2f(h.z));
        h.w = f2bf(x.w); lw.w = f2bf(x.w - bf2f(h.w));
        ((ushort4*)hi)[i] = h;
        ((ushort4*)lo)[i] = lw;
    }
}

// ---------------------------------------------------------------------------
// values [2048][32][1024] f32 -> per batch-group:
//   vhi/vlo [(s*gc+bi)][1024] bf16 pair  (K2 B-operand, NT)
//   vT [bi][1024][2048] bf16             (K4 B-operand, NT)
// ---------------------------------------------------------------------------
__global__ __launch_bounds__(256) void values_conv_k(
    const float* __restrict__ values,
    ushort* __restrict__ vhi, ushort* __restrict__ vlo, ushort* __restrict__ vT,
    int b0, int gc)
{
    __shared__ float tile[64][65];
    const int t  = threadIdx.x;
    const int s0 = blockIdx.x * 64;
    const int v0 = blockIdx.y * 64;
    const int bi = blockIdx.z;
    const int b  = b0 + bi;
#pragma unroll
    for (int i = 0; i < 4; ++i) {
        int c = t + i * 256;
        int r = c >> 4;
        int qq = c & 15;
        float4 x = *(const float4*)(values + ((long)(s0 + r) * 32 + b) * 1024 + v0 + qq * 4);
        ushort4 h, lw;
        h.x = f2bf(x.x); lw.x = f2bf(x.x - bf2f(h.x));
        h.y = f2bf(x.y); lw.y = f2bf(x.y - bf2f(h.y));
        h.z = f2bf(x.z); lw.z = f2bf(x.z - bf2f(h.z));
        h.w = f2bf(x.w); lw.w = f2bf(x.w - bf2f(h.w));
        long rowoff = ((long)(s0 + r) * gc + bi) * 1024 + v0 + qq * 4;
        *(ushort4*)(vhi + rowoff) = h;
        *(ushort4*)(vlo + rowoff) = lw;
        tile[r][qq * 4 + 0] = x.x;
        tile[r][qq * 4 + 1] = x.y;
        tile[r][qq * 4 + 2] = x.z;
        tile[r][qq * 4 + 3] = x.w;
    }
    __syncthreads();
    const int vr = t >> 2;
    const int ss = (t & 3) * 16;
    ushort* dst = vT + ((long)bi * 1024 + v0 + vr) * 2048 + s0 + ss;
#pragma unroll
    for (int j = 0; j < 4; ++j) {
        ushort4 o;
        o.x = f2bf(tile[ss + j * 4 + 0][vr]);
        o.y = f2bf(tile[ss + j * 4 + 1][vr]);
        o.z = f2bf(tile[ss + j * 4 + 2][vr]);
        o.w = f2bf(tile[ss + j * 4 + 3][vr]);
        *(ushort4*)(dst + j * 4) = o;
    }
}

// softmax over 2048-rows, f32 in -> bf16 P out. One 256-thread block per row.
__global__ __launch_bounds__(256) void softmax2048b_k(
    const float* __restrict__ S, ushort* __restrict__ P)
{
    __shared__ float red[4];
    const long row = blockIdx.x;
    const float* p = S + row * 2048 + threadIdx.x * 8;
    float4 a = ((const float4*)p)[0];
    float4 b = ((const float4*)p)[1];

    float m = fmaxf(fmaxf(fmaxf(a.x, a.y), fmaxf(a.z, a.w)),
                    fmaxf(fmaxf(b.x, b.y), fmaxf(b.z, b.w)));
#pragma unroll
    for (int off = 32; off; off >>= 1) m = fmaxf(m, __shfl_xor(m, off));
    int wid = threadIdx.x >> 6;
    if ((threadIdx.x & 63) == 0) red[wid] = m;
    __syncthreads();
    m = fmaxf(fmaxf(red[0], red[1]), fmaxf(red[2], red[3]));
    __syncthreads();

    a.x = __expf(a.x - m); a.y = __expf(a.y - m);
    a.z = __expf(a.z - m); a.w = __expf(a.w - m);
    b.x = __expf(b.x - m); b.y = __expf(b.y - m);
    b.z = __expf(b.z - m); b.w = __expf(b.w - m);

    float s = a.x + a.y + a.z + a.w + b.x + b.y + b.z + b.w;
#pragma unroll
    for (int off = 32; off; off >>= 1) s += __shfl_xor(s, off);
    if ((threadIdx.x & 63) == 0) red[wid] = s;
    __syncthreads();
    s = red[0] + red[1] + red[2] + red[3];
    float inv = 1.0f / s;

    ushort* qp = P + row * 2048 + threadIdx.x * 8;
    ushort4 oA, oB;
    oA.x = f2bf(a.x * inv); oA.y = f2bf(a.y * inv);
    oA.z = f2bf(a.z * inv); oA.w = f2bf(a.w * inv);
    oB.x = f2bf(b.x * inv); oB.y = f2bf(b.y * inv);
    oB.z = f2bf(b.z * inv); oB.w = f2bf(b.w * inv);
    ((ushort4*)qp)[0] = oA;
    ((ushort4*)qp)[1] = oB;
}

// ===========================================================================
// Fallback fp32 path (used only if ws_size is too small)
// ===========================================================================
#define BM 128
#define BN 128
#define BK 16

template<bool NT, int MODE>
__global__ __launch_bounds__(256) void gemm_f32(
    const float* __restrict__ A, const float* __restrict__ A2, int Ksplit,
    const float* __restrict__ Bm, const float* __restrict__ bias,
    float* __restrict__ C,
    long lda, long ldb, long ldc, int K,
    long sAb, long sBb, long sCb)
{
    __shared__ float As[BK][BM + 4];
    __shared__ float Bs[BK][BN + 4];

    const int bz = blockIdx.z;
    const float* Ab  = A + (long)bz * sAb;
    const float* A2b = A2 ? (A2 + (long)bz * sAb) : nullptr;
    const float* Bb  = Bm + (long)bz * sBb;
    float*       Cb  = C + (long)bz * sCb;

    const int m0 = blockIdx.y * BM;
    const int n0 = blockIdx.x * BN;
    const int t  = threadIdx.x;
    const int tx = t & 15;
    const int ty = t >> 4;

    float acc[8][8];
#pragma unroll
    for (int i = 0; i < 8; ++i)
#pragma unroll
        for (int j = 0; j < 8; ++j) acc[i][j] = 0.f;

    for (int k0 = 0; k0 < K; k0 += BK) {
        const float* Asrc = (A2b && k0 >= Ksplit) ? (A2b - Ksplit) : Ab;
#pragma unroll
        for (int c = 0; c < 2; ++c) {
            int chunk = t + c * 256;
            int row = chunk >> 2;
            int kq  = chunk & 3;
            float4 v = *(const float4*)(Asrc + (long)(m0 + row) * lda + k0 + kq * 4);
            As[kq * 4 + 0][row] = v.x;
            As[kq * 4 + 1][row] = v.y;
            As[kq * 4 + 2][row] = v.z;
            As[kq * 4 + 3][row] = v.w;
        }
        if (NT) {
#pragma unroll
            for (int c = 0; c < 2; ++c) {
                int chunk = t + c * 256;
                int row = chunk >> 2;
                int kq  = chunk & 3;
                float4 v = *(const float4*)(Bb + (long)(n0 + row) * ldb + k0 + kq * 4);
                Bs[kq * 4 + 0][row] = v.x;
                Bs[kq * 4 + 1][row] = v.y;
                Bs[kq * 4 + 2][row] = v.z;
                Bs[kq * 4 + 3][row] = v.w;
            }
        } else {
#pragma unroll
            for (int c = 0; c < 2; ++c) {
                int chunk = t + c * 256;
                int kr = chunk >> 5;
                int vq = chunk & 31;
                float4 v = *(const float4*)(Bb + (long)(k0 + kr) * ldb + n0 + vq * 4);
                *(float4*)&Bs[kr][vq * 4] = v;
            }
        }
        __syncthreads();

#pragma unroll
        for (int k = 0; k < BK; ++k) {
            float4 a0 = *(const float4*)&As[k][ty * 8];
            float4 a1 = *(const float4*)&As[k][ty * 8 + 4];
            float4 b0 = *(const float4*)&Bs[k][tx * 8];
            float4 b1 = *(const float4*)&Bs[k][tx * 8 + 4];
            float ar[8] = {a0.x, a0.y, a0.z, a0.w, a1.x, a1.y, a1.z, a1.w};
            float br[8] = {b0.x, b0.y, b0.z, b0.w, b1.x, b1.y, b1.z, b1.w};
#pragma unroll
            for (int i = 0; i < 8; ++i)
#pragma unroll
                for (int j = 0; j < 8; ++j)
                    acc[i][j] += ar[i] * br[j];
        }
        __syncthreads();
    }

    float brow[8];
    if (MODE >= 1) {
#pragma unroll
        for (int j = 0; j < 8; ++j) brow[j] = bias[n0 + tx * 8 + j];
    }
#pragma unroll
    for (int i = 0; i < 8; ++i) {
        long row = m0 + ty * 8 + i;
        float v[8];
#pragma unroll
        for (int j = 0; j < 8; ++j) {
            float x = acc[i][j];
            if (MODE >= 1) x += brow[j];
            if (MODE == 2) x = tanhf(x);
            v[j] = x;
        }
        float4* dst = (float4*)&Cb[row * ldc + n0 + tx * 8];
        dst[0] = make_float4(v[0], v[1], v[2], v[3]);
        dst[1] = make_float4(v[4], v[5], v[6], v[7]);
    }
}

__global__ __launch_bounds__(256) void softmax2048(float* __restrict__ S)
{
    __shared__ float red[4];
    float* p = S + (long)blockIdx.x * 2048 + threadIdx.x * 8;
    float4 a = ((float4*)p)[0];
    float4 b = ((float4*)p)[1];

    float m = fmaxf(fmaxf(fmaxf(a.x, a.y), fmaxf(a.z, a.w)),
                    fmaxf(fmaxf(b.x, b.y), fmaxf(b.z, b.w)));
#pragma unroll
    for (int off = 32; off; off >>= 1) m = fmaxf(m, __shfl_xor(m, off));
    int wid = threadIdx.x >> 6;
    if ((threadIdx.x & 63) == 0) red[wid] = m;
    __syncthreads();
    m = fmaxf(fmaxf(red[0], red[1]), fmaxf(red[2], red[3]));
    __syncthreads();

    a.x = __expf(a.x - m); a.y = __expf(a.y - m);
    a.z = __expf(a.z - m); a.w = __expf(a.w - m);
    b.x = __expf(b.x - m); b.y = __expf(b.y - m);
    b.z = __expf(b.z - m); b.w = __expf(b.w - m);

    float s = a.x + a.y + a.z + a.w + b.x + b.y + b.z + b.w;
#pragma unroll
    for (int off = 32; off; off >>= 1) s += __shfl_xor(s, off);
    if ((threadIdx.x & 63) == 0) red[wid] = s;
    __syncthreads();
    s = red[0] + red[1] + red[2] + red[3];
    float inv = 1.0f / s;

    a.x *= inv; a.y *= inv; a.z *= inv; a.w *= inv;
    b.x *= inv; b.y *= inv; b.z *= inv; b.w *= inv;
    ((float4*)p)[0] = a;
    ((float4*)p)[1] = b;
}

// ===========================================================================
extern "C" void kernel_launch(void* const* d_in, const int* in_sizes, int n_in,
                              void* d_out, int out_size, void* d_ws, size_t ws_size,
                              hipStream_t stream)
{
    const float* query  = (const float*)d_in[0];
    const float* values = (const float*)d_in[1];
    const float* W1     = (const float*)d_in[2];
    const float* b1     = (const float*)d_in[3];
    const float* W2     = (const float*)d_in[4];
    const float* b2     = (const float*)d_in[5];
    float* out = (float*)d_out;

    const int Bc = 32, QL = 512, SL = 2048, D = 1024, F = 2048;
    const long R = (long)QL * Bc;   // 16384

    char* p = (char*)d_ws;
    auto take = [&](size_t bytes) -> char* {
        char* r = p;
        p += (bytes + 255) & ~(size_t)255;
        return r;
    };

    ushort* q_hi  = (ushort*)take((size_t)R * D * 2);
    ushort* q_lo  = (ushort*)take((size_t)R * D * 2);
    ushort* w1_hi = (ushort*)take((size_t)D * D * 2);
    ushort* w1_lo = (ushort*)take((size_t)D * D * 2);
    ushort* w2_hi = (ushort*)take((size_t)D * F * 2);
    ushort* w2_lo = (ushort*)take((size_t)D * F * 2);
    ushort* qr_hi = (ushort*)take((size_t)R * D * 2);
    ushort* qr_lo = (ushort*)take((size_t)R * D * 2);
    ushort* at_hi = (ushort*)take((size_t)R * D * 2);
    size_t fixedBytes = (size_t)(p - (char*)d_ws);

    // per batch: vals hi+lo+vT (3 x 4 MB) + scores f32 (4 MB) + P bf16 (2 MB)
    const size_t perBatch = (size_t)SL * D * 2 * 3 + (size_t)QL * SL * 4 + (size_t)QL * SL * 2 + 2048;
    long availB = (long)ws_size - (long)fixedBytes;
    int g = availB > 0 ? (int)(availB / (long)perBatch) : 0;
    if (g > 32) g = 32;

    if (g >= 1) {
        // ----------------------- fast split-bf16 MFMA path -----------------
        ushort* vals_hi = (ushort*)take((size_t)SL * D * 2 * g);
        ushort* vals_lo = (ushort*)take((size_t)SL * D * 2 * g);
        ushort* vT      = (ushort*)take((size_t)SL * D * 2 * g);
        float*  scores  = (float*) take((size_t)QL * SL * 4 * g);
        ushort* P       = (ushort*)take((size_t)QL * SL * 2 * g);

        split_pair_k<<<2048, 256, 0, stream>>>(query, q_hi, q_lo, R * D / 4);
        split_pair_k<<<1024, 256, 0, stream>>>(W1, w1_hi, w1_lo, (long)D * D / 4);
        split_pair_k<<<1024, 256, 0, stream>>>(W2, w2_hi, w2_lo, (long)D * F / 4);

        // K1: qr = query.W1^T + b1  (3-term split segments) -> bf16 pair
        gemm256p<2><<<dim3(D / 256, R / 256, 1), 512, 0, stream>>>(
            q_hi, q_hi, q_lo, w1_hi, w1_lo, w1_hi,
            D, D, 32, 3, b1,
            nullptr, qr_hi, qr_lo,
            D, 0, 0, 0);

        for (int b0 = 0; b0 < Bc; b0 += g) {
            int gc = (Bc - b0 < g) ? (Bc - b0) : g;

            values_conv_k<<<dim3(SL / 64, D / 64, gc), 256, 0, stream>>>(
                values, vals_hi, vals_lo, vT, b0, gc);

            // K2: scores[bi,q,s] = qr . values  (3-term split segments) -> f32
            gemm256p<0><<<dim3(SL / 256, QL / 256, gc), 512, 0, stream>>>(
                qr_hi + (size_t)b0 * D, qr_hi + (size_t)b0 * D, qr_lo + (size_t)b0 * D,
                vals_hi, vals_lo, vals_hi,
                (long)Bc * D, (long)gc * D, 32, 3, nullptr,
                scores, nullptr, nullptr,
                SL, D, D, (long)QL * SL);

            softmax2048b_k<<<gc * QL, 256, 0, stream>>>(scores, P);

            // K4: att = P . vT  (1-term) -> bf16 hi only
            gemm256p<2><<<dim3(D / 256, QL / 256, gc), 512, 0, stream>>>(
                P, P, P, vT, vT, vT,
                SL, SL, 64, 1, nullptr,
                nullptr, at_hi + (size_t)b0 * D, nullptr,
                (long)Bc * D, (long)QL * SL, (long)D * SL, D);
        }

        // K5: out = tanh([att | query] . W2^T + b2)  (1-term, 2 K-segments)
        gemm256p<3><<<dim3(D / 256, R / 256, 1), 512, 0, stream>>>(
            at_hi, q_hi, q_hi, w2_hi, w2_hi + 1024, w2_hi,
            D, F, 32, 2, b2,
            out, nullptr, nullptr,
            D, 0, 0, 0);
        return;
    }

    // ----------------------- fp32 fallback ---------------------------------
    float* qr = (float*)d_ws;
    size_t qrBytes = (size_t)R * D * sizeof(float);
    float* sc = (float*)((char*)d_ws + qrBytes);
    size_t scPerB = (size_t)QL * SL * sizeof(float);

    int grp = 32;
    if (ws_size < qrBytes + 32 * scPerB) {
        size_t avail = ws_size > qrBytes ? ws_size - qrBytes : 0;
        grp = (int)(avail / scPerB);
        if (grp < 1)  grp = 1;
        if (grp > 32) grp = 32;
    }

    {
        dim3 gd(D / BN, R / BM, 1);
        gemm_f32<true, 1><<<gd, 256, 0, stream>>>(
            query, nullptr, 1 << 30, W1, b1, qr,
            D, D, D, D, 0, 0, 0);
    }
    for (int b0 = 0; b0 < Bc; b0 += grp) {
        int gg = (Bc - b0 < grp) ? (Bc - b0) : grp;
        {
            dim3 gd(SL / BN, QL / BM, gg);
            gemm_f32<true, 0><<<gd, 256, 0, stream>>>(
                qr + (size_t)b0 * D, nullptr, 1 << 30,
                values + (size_t)b0 * D, nullptr, sc,
                (long)Bc * D, (long)Bc * D, SL, D,
                D, D, (long)QL * SL);
        }
        softmax2048<<<gg * QL, 256, 0, stream>>>(sc);
        {
            dim3 gd(D / BN, QL / BM, gg);
            gemm_f32<false, 0><<<gd, 256, 0, stream>>>(
                sc, nullptr, 1 << 30,
                values + (size_t)b0 * D, nullptr, qr + (size_t)b0 * D,
                SL, (long)Bc * D, (long)Bc * D, SL,
                (long)QL * SL, D, D);
        }
    }
    {
        dim3 gd(D / BN, R / BM, 1);
        gemm_f32<true, 2><<<gd, 256, 0, stream>>>(
            qr, query, D, W2, b2, out,
            D, 2048, D, 2048, 0, 0, 0);
    }
}